// Round 1
// baseline (918.069 us; speedup 1.0000x reference)
//
#include <hip/hip_runtime.h>
#include <math.h>

typedef float f32x4 __attribute__((ext_vector_type(4)));

#define DD 256
#define DH 128
#define M_TILE 32
#define XS_LD 260   // padded LDS row stride (floats) to break bank conflicts
#define K_CHUNK 64

// order-preserving float<->uint encoding for deterministic atomicMax
__device__ __forceinline__ unsigned enc_f32(float f) {
  unsigned u = __float_as_uint(f);
  return (u & 0x80000000u) ? ~u : (u | 0x80000000u);
}
__device__ __forceinline__ float dec_f32(unsigned u) {
  return __uint_as_float((u & 0x80000000u) ? (u ^ 0x80000000u) : ~u);
}

__global__ void ap_init(unsigned* maxslot) { *maxslot = 0u; }

// ---------------------------------------------------------------------------
// K1: raw[i] = relu(x[i] @ W1 + b1) @ W2 + b2, plus global max via atomicMax.
// 32-row tile in LDS (padded), W1 streamed in 64-k chunks, 2x8 microtile.
// ---------------------------------------------------------------------------
__global__ __launch_bounds__(256, 2)
void ap_mlp(const float* __restrict__ x, const float* __restrict__ W1,
            const float* __restrict__ b1, const float* __restrict__ W2,
            const float* __restrict__ b2, float* __restrict__ raw,
            unsigned* __restrict__ maxslot, int nrows) {
  __shared__ __align__(16) float xs[M_TILE * XS_LD];   // 33.3 KB
  __shared__ __align__(16) float w1s[K_CHUNK * DH];    // 32 KB
  __shared__ float red[M_TILE * 16];
  __shared__ float red2[M_TILE];

  const int tid = threadIdx.x;
  const int colg = tid & 15;   // 16 col-groups of 8 columns
  const int rowg = tid >> 4;   // 16 row-groups of 2 rows
  const int c0 = colg * 8;
  const long long row0 = (long long)blockIdx.x * M_TILE;

  float b1f[8], w2f[8];
#pragma unroll
  for (int j = 0; j < 8; ++j) { b1f[j] = b1[c0 + j]; w2f[j] = W2[c0 + j]; }

  // stage x tile into padded LDS rows (coalesced float4 loads)
  for (int j = tid; j < M_TILE * (DD / 4); j += 256) {
    const int r = j >> 6;            // 64 float4 per row
    const int c4 = (j & 63) << 2;
    long long grow = row0 + r;
    if (grow > (long long)nrows - 1) grow = nrows - 1;  // clamp (masked later)
    f32x4 v = *(const f32x4*)(x + grow * DD + c4);
    *(f32x4*)(xs + r * XS_LD + c4) = v;
  }

  float acc0[8], acc1[8];
#pragma unroll
  for (int j = 0; j < 8; ++j) { acc0[j] = 0.f; acc1[j] = 0.f; }

  const float* xr0 = xs + (rowg * 2) * XS_LD;
  const float* xr1 = xr0 + XS_LD;

  for (int kc = 0; kc < DD; kc += K_CHUNK) {
    __syncthreads();  // previous chunk fully consumed (also covers x staging)
    for (int j = tid; j < K_CHUNK * (DH / 4); j += 256) {
      f32x4 v = *(const f32x4*)(W1 + kc * DH + 4 * j);
      *(f32x4*)(w1s + 4 * j) = v;
    }
    __syncthreads();

#pragma unroll 4
    for (int kq = 0; kq < K_CHUNK / 4; ++kq) {
      const f32x4 xa = *(const f32x4*)(xr0 + kc + 4 * kq);
      const f32x4 xb = *(const f32x4*)(xr1 + kc + 4 * kq);
#pragma unroll
      for (int j = 0; j < 4; ++j) {
        const f32x4 wA = *(const f32x4*)(w1s + (kq * 4 + j) * DH + c0);
        const f32x4 wB = *(const f32x4*)(w1s + (kq * 4 + j) * DH + c0 + 4);
        const float xaj = xa[j], xbj = xb[j];
#pragma unroll
        for (int cc = 0; cc < 4; ++cc) {
          acc0[cc]     += xaj * wA[cc];
          acc0[cc + 4] += xaj * wB[cc];
          acc1[cc]     += xbj * wA[cc];
          acc1[cc + 4] += xbj * wB[cc];
        }
      }
    }
  }

  // epilogue: relu + dot with W2, reduce 16 col-groups per row
  float pr0 = 0.f, pr1 = 0.f;
#pragma unroll
  for (int j = 0; j < 8; ++j) {
    pr0 += fmaxf(acc0[j] + b1f[j], 0.f) * w2f[j];
    pr1 += fmaxf(acc1[j] + b1f[j], 0.f) * w2f[j];
  }
  red[(rowg * 2 + 0) * 16 + colg] = pr0;
  red[(rowg * 2 + 1) * 16 + colg] = pr1;
  __syncthreads();
  if (tid < M_TILE) {
    float s = b2[0];
#pragma unroll
    for (int g = 0; g < 16; ++g) s += red[tid * 16 + g];
    const long long r = row0 + tid;
    if (r < nrows) { raw[r] = s; red2[tid] = s; }
    else { red2[tid] = -3.4e38f; }
  }
  __syncthreads();
  if (tid == 0) {
    float m = red2[0];
#pragma unroll
    for (int i = 1; i < M_TILE; ++i) m = fmaxf(m, red2[i]);
    atomicMax(maxslot, enc_f32(m));
  }
}

// ---------------------------------------------------------------------------
// K2: segment boundaries (batch is sorted). start[b] = first i with batch[i]>=b
// ---------------------------------------------------------------------------
__global__ void ap_bounds(const int* __restrict__ batch, int* __restrict__ start,
                          int nrows, int bseg) {
  int i = blockIdx.x * blockDim.x + threadIdx.x;
  if (i >= nrows) return;
  int c = batch[i];
  int p = (i == 0) ? -1 : batch[i - 1];
  for (int b = p + 1; b <= c; ++b) start[b] = i;
  if (i == nrows - 1) {
    for (int b = c + 1; b <= bseg; ++b) start[b] = nrows;
  }
}

// ---------------------------------------------------------------------------
// K3: per-segment w = exp(raw - M), sum_w, and final per-segment scale
//     scale[b] = 1 / ((mean_w * N + 1e-8) * max(cnt,1))
// ---------------------------------------------------------------------------
__global__ __launch_bounds__(256)
void ap_segw(const float* __restrict__ raw, const int* __restrict__ start,
             const unsigned* __restrict__ maxslot, float* __restrict__ w,
             float* __restrict__ scale, int nrows) {
  __shared__ float sred[256];
  const int b = blockIdx.x;
  const int s = start[b], e = start[b + 1];
  const float M = dec_f32(*maxslot);
  float acc = 0.f;
  for (int i = s + (int)threadIdx.x; i < e; i += 256) {
    float wv = expf(raw[i] - M);
    w[i] = wv;
    acc += wv;
  }
  sred[threadIdx.x] = acc;
  __syncthreads();
  for (int off = 128; off > 0; off >>= 1) {
    if ((int)threadIdx.x < off) sred[threadIdx.x] += sred[threadIdx.x + off];
    __syncthreads();
  }
  if (threadIdx.x == 0) {
    const float sum = sred[0];
    const int cnt = e - s;
    const float cntf = (float)(cnt > 0 ? cnt : 1);
    const float mean = sum / cntf;
    const float dpe = mean * (float)nrows + 1e-8f;
    scale[b] = 1.0f / (dpe * cntf);
  }
}

// ---------------------------------------------------------------------------
// K4: pooled[b][:] = (sum_{i in seg} w[i] * x[i][:]) * scale[b]
// block per segment; 4 row-groups x 64 lanes x float4 -> full coalesced rows
// ---------------------------------------------------------------------------
__global__ __launch_bounds__(256)
void ap_pool(const float* __restrict__ x, const float* __restrict__ w,
             const int* __restrict__ start, const float* __restrict__ scale,
             float* __restrict__ out) {
  __shared__ f32x4 sred[4][64];
  const int b = blockIdx.x;
  const int s = start[b], e = start[b + 1];
  const int dq = threadIdx.x & 63;
  const int rg = threadIdx.x >> 6;
  f32x4 acc = {0.f, 0.f, 0.f, 0.f};
  for (int i = s + rg; i < e; i += 4) {
    const float wv = w[i];
    const f32x4 xv = *(const f32x4*)(x + (long long)i * DD + dq * 4);
    acc += xv * wv;
  }
  sred[rg][dq] = acc;
  __syncthreads();
  if (rg == 0) {
    f32x4 r = ((sred[0][dq] + sred[1][dq]) + sred[2][dq]) + sred[3][dq];
    r *= scale[b];
    *(f32x4*)(out + (long long)b * DD + dq * 4) = r;
  }
}

extern "C" void kernel_launch(void* const* d_in, const int* in_sizes, int n_in,
                              void* d_out, int out_size, void* d_ws, size_t ws_size,
                              hipStream_t stream) {
  const float* x     = (const float*)d_in[0];
  const int*   batch = (const int*)d_in[1];
  const float* W1    = (const float*)d_in[2];
  const float* b1    = (const float*)d_in[3];
  const float* W2    = (const float*)d_in[4];
  const float* b2    = (const float*)d_in[5];
  float* out = (float*)d_out;

  const int nrows = in_sizes[1];
  const int bseg = out_size / DD;

  // workspace layout (all written before read every call)
  float* raw = (float*)d_ws;
  float* w = raw + nrows;
  float* scale = w + nrows;
  int* start = (int*)(scale + bseg);
  unsigned* maxslot = (unsigned*)(start + bseg + 1);

  ap_init<<<1, 1, 0, stream>>>(maxslot);
  ap_mlp<<<(nrows + M_TILE - 1) / M_TILE, 256, 0, stream>>>(x, W1, b1, W2, b2, raw,
                                                            maxslot, nrows);
  ap_bounds<<<(nrows + 255) / 256, 256, 0, stream>>>(batch, start, nrows, bseg);
  ap_segw<<<bseg, 256, 0, stream>>>(raw, start, maxslot, w, scale, nrows);
  ap_pool<<<bseg, 256, 0, stream>>>(x, w, start, scale, out);
}

// Round 2
// 362.807 us; speedup vs baseline: 2.5305x; 2.5305x over previous
//
#include <hip/hip_runtime.h>
#include <math.h>

typedef float f32x4 __attribute__((ext_vector_type(4)));
typedef __attribute__((ext_vector_type(8))) short bf16x8;

#define DD 256
#define DH 128

// order-preserving float<->uint encoding for deterministic atomicMax
__device__ __forceinline__ unsigned enc_f32(float f) {
  unsigned u = __float_as_uint(f);
  return (u & 0x80000000u) ? ~u : (u | 0x80000000u);
}
__device__ __forceinline__ float dec_f32(unsigned u) {
  return __uint_as_float((u & 0x80000000u) ? (u ^ 0x80000000u) : ~u);
}
// fp32 -> bf16 bits, round-to-nearest-even
__device__ __forceinline__ unsigned short f2bf_rne(float f) {
  unsigned u = __float_as_uint(f);
  unsigned r = (u + 0x7fffu + ((u >> 16) & 1u)) >> 16;
  return (unsigned short)r;
}

__global__ void ap_init(unsigned* maxslot) { *maxslot = 0u; }

// ---------------------------------------------------------------------------
// K0: convert W1 (256x128 fp32 row-major) into MFMA B-fragment order, split
// into bf16 hi + lo. Layout: w1hi[((kt*8+nt)*64 + lane)*8 + j] where the
// fragment element is W1[kt*32 + (lane>>4)*8 + j][nt*16 + (lane&15)].
// ---------------------------------------------------------------------------
__global__ void ap_prep(const float* __restrict__ W1,
                        unsigned short* __restrict__ w1hi,
                        unsigned short* __restrict__ w1lo) {
  int t = blockIdx.x * blockDim.x + threadIdx.x;  // 0..4095
  if (t >= 64 * 64) return;
  int l = t & 63;
  int tile = t >> 6;  // kt*8 + nt
  int kt = tile >> 3, nt = tile & 7;
  int kbase = kt * 32 + (l >> 4) * 8;
  int col = nt * 16 + (l & 15);
#pragma unroll
  for (int j = 0; j < 8; ++j) {
    float f = W1[(kbase + j) * DH + col];
    unsigned short h = f2bf_rne(f);
    float hf = __uint_as_float((unsigned)h << 16);
    unsigned short lb = f2bf_rne(f - hf);
    w1hi[t * 8 + j] = h;
    w1lo[t * 8 + j] = lb;
  }
}

// ---------------------------------------------------------------------------
// K1: raw[i] = relu(x[i] @ W1 + b1) @ W2 + b2 via split-bf16 MFMA.
// Block = 256 threads = 4 waves; wave w owns rows blk*64 + 16w .. +16.
// A-fragments loaded directly from global x (fp32 -> bf16 hi/lo in-reg);
// B-fragments from the prepped layout (L2-resident). No GEMM LDS.
// ---------------------------------------------------------------------------
__global__ __launch_bounds__(256)
void ap_mlp(const float* __restrict__ x, const unsigned short* __restrict__ w1hi,
            const unsigned short* __restrict__ w1lo, const float* __restrict__ b1,
            const float* __restrict__ W2, const float* __restrict__ b2,
            float* __restrict__ raw, unsigned* __restrict__ maxslot, int nrows) {
  const int tid = threadIdx.x;
  const int wv = tid >> 6;
  const int l = tid & 63;
  const int l15 = l & 15, lhi = l >> 4;

  long long row = (long long)blockIdx.x * 64 + wv * 16 + l15;
  long long rowc = row < (long long)nrows ? row : (long long)nrows - 1;
  const float* xr = x + rowc * DD + lhi * 8;

  float b1f[8], w2f[8];
#pragma unroll
  for (int nt = 0; nt < 8; ++nt) {
    b1f[nt] = b1[nt * 16 + l15];
    w2f[nt] = W2[nt * 16 + l15];
  }

  f32x4 acc[8];
#pragma unroll
  for (int nt = 0; nt < 8; ++nt) acc[nt] = f32x4{0.f, 0.f, 0.f, 0.f};

  for (int kt = 0; kt < 8; ++kt) {
    const f32x4 v0 = *(const f32x4*)(xr + kt * 32);
    const f32x4 v1 = *(const f32x4*)(xr + kt * 32 + 4);
    bf16x8 ah, al;
#pragma unroll
    for (int j = 0; j < 8; ++j) {
      float f = (j < 4) ? v0[j] : v1[j - 4];
      unsigned short h = f2bf_rne(f);
      float hf = __uint_as_float((unsigned)h << 16);
      ah[j] = (short)h;
      al[j] = (short)f2bf_rne(f - hf);
    }
    const bf16x8* bh = (const bf16x8*)(w1hi + (size_t)kt * 4096);
    const bf16x8* bl = (const bf16x8*)(w1lo + (size_t)kt * 4096);
#pragma unroll
    for (int nt = 0; nt < 8; ++nt) {
      const bf16x8 Bh = bh[nt * 64 + l];
      const bf16x8 Bl = bl[nt * 64 + l];
      acc[nt] = __builtin_amdgcn_mfma_f32_16x16x32_bf16(ah, Bh, acc[nt], 0, 0, 0);
      acc[nt] = __builtin_amdgcn_mfma_f32_16x16x32_bf16(al, Bh, acc[nt], 0, 0, 0);
      acc[nt] = __builtin_amdgcn_mfma_f32_16x16x32_bf16(ah, Bl, acc[nt], 0, 0, 0);
    }
  }

  // epilogue: acc[nt][r] = H[lhi*4 + r][nt*16 + l15] (C/D: col=lane&15,
  // row=(lane>>4)*4+reg). relu + b1, dot W2, reduce over the 16 col-lanes.
  float pr[4];
#pragma unroll
  for (int r = 0; r < 4; ++r) {
    float s = 0.f;
#pragma unroll
    for (int nt = 0; nt < 8; ++nt) s += fmaxf(acc[nt][r] + b1f[nt], 0.f) * w2f[nt];
    pr[r] = s;
  }
#pragma unroll
  for (int m = 1; m < 16; m <<= 1) {
#pragma unroll
    for (int r = 0; r < 4; ++r) pr[r] += __shfl_xor(pr[r], m, 64);
  }
  const float bb = *b2;
  const long long wrow0 = (long long)blockIdx.x * 64 + wv * 16 + lhi * 4;
  float mymax = -3.4e38f;
#pragma unroll
  for (int r = 0; r < 4; ++r) {
    float s = pr[r] + bb;
    long long rr = wrow0 + r;
    if (rr < (long long)nrows) {
      if (l15 == 0) raw[rr] = s;
      mymax = fmaxf(mymax, s);
    }
  }
  mymax = fmaxf(mymax, __shfl_xor(mymax, 16, 64));
  mymax = fmaxf(mymax, __shfl_xor(mymax, 32, 64));
  __shared__ float wmax[4];
  if (l == 0) wmax[wv] = mymax;
  __syncthreads();
  if (tid == 0) {
    float m = fmaxf(fmaxf(wmax[0], wmax[1]), fmaxf(wmax[2], wmax[3]));
    atomicMax(maxslot, enc_f32(m));
  }
}

// ---------------------------------------------------------------------------
// K2: segment boundaries (batch sorted). start[b] = first i with batch[i]>=b
// ---------------------------------------------------------------------------
__global__ void ap_bounds(const int* __restrict__ batch, int* __restrict__ start,
                          int nrows, int bseg) {
  int i = blockIdx.x * blockDim.x + threadIdx.x;
  if (i >= nrows) return;
  int c = batch[i];
  int p = (i == 0) ? -1 : batch[i - 1];
  for (int b = p + 1; b <= c; ++b) start[b] = i;
  if (i == nrows - 1) {
    for (int b = c + 1; b <= bseg; ++b) start[b] = nrows;
  }
}

// ---------------------------------------------------------------------------
// K3: per-segment sum of w = exp(raw - M); scale[b] = 1/((mean_w*N+1e-8)*cnt)
// (w is NOT stored; ap_pool recomputes exp — saves ws + 4 MB of traffic)
// ---------------------------------------------------------------------------
__global__ __launch_bounds__(256)
void ap_segw(const float* __restrict__ raw, const int* __restrict__ start,
             const unsigned* __restrict__ maxslot, float* __restrict__ scale,
             int nrows) {
  __shared__ float sred[256];
  const int b = blockIdx.x;
  const int s = start[b], e = start[b + 1];
  const float M = dec_f32(*maxslot);
  float acc = 0.f;
  for (int i = s + (int)threadIdx.x; i < e; i += 256) acc += expf(raw[i] - M);
  sred[threadIdx.x] = acc;
  __syncthreads();
  for (int off = 128; off > 0; off >>= 1) {
    if ((int)threadIdx.x < off) sred[threadIdx.x] += sred[threadIdx.x + off];
    __syncthreads();
  }
  if (threadIdx.x == 0) {
    const float sum = sred[0];
    const int cnt = e - s;
    const float cntf = (float)(cnt > 0 ? cnt : 1);
    const float mean = sum / cntf;
    const float dpe = mean * (float)nrows + 1e-8f;
    scale[b] = 1.0f / (dpe * cntf);
  }
}

// ---------------------------------------------------------------------------
// K4: pooled[b][:] = (sum_{i in seg} exp(raw[i]-M) * x[i][:]) * scale[b]
// ---------------------------------------------------------------------------
__global__ __launch_bounds__(256)
void ap_pool(const float* __restrict__ x, const float* __restrict__ raw,
             const int* __restrict__ start, const float* __restrict__ scale,
             const unsigned* __restrict__ maxslot, float* __restrict__ out) {
  __shared__ f32x4 sred[4][64];
  const int b = blockIdx.x;
  const int s = start[b], e = start[b + 1];
  const float M = dec_f32(*maxslot);
  const int dq = threadIdx.x & 63;
  const int rg = threadIdx.x >> 6;
  f32x4 acc = {0.f, 0.f, 0.f, 0.f};
  for (int i = s + rg; i < e; i += 4) {
    const float wv = expf(raw[i] - M);
    const f32x4 xv = *(const f32x4*)(x + (long long)i * DD + dq * 4);
    acc += xv * wv;
  }
  sred[rg][dq] = acc;
  __syncthreads();
  if (rg == 0) {
    f32x4 r = ((sred[0][dq] + sred[1][dq]) + sred[2][dq]) + sred[3][dq];
    r *= scale[b];
    *(f32x4*)(out + (long long)b * DD + dq * 4) = r;
  }
}

extern "C" void kernel_launch(void* const* d_in, const int* in_sizes, int n_in,
                              void* d_out, int out_size, void* d_ws, size_t ws_size,
                              hipStream_t stream) {
  const float* x     = (const float*)d_in[0];
  const int*   batch = (const int*)d_in[1];
  const float* W1    = (const float*)d_in[2];
  const float* b1    = (const float*)d_in[3];
  const float* W2    = (const float*)d_in[4];
  const float* b2    = (const float*)d_in[5];
  float* out = (float*)d_out;

  const int nrows = in_sizes[1];
  const int bseg = out_size / DD;

  // workspace layout (16B-aligned fragment arrays first)
  unsigned short* w1hi = (unsigned short*)d_ws;              // 64 KB
  unsigned short* w1lo = w1hi + 64 * 64 * 8;                 // 64 KB
  float* raw = (float*)(w1lo + 64 * 64 * 8);                 // nrows fp32
  float* scale = raw + nrows;                                // bseg fp32
  int* start = (int*)(scale + bseg);                         // bseg+1 ints
  unsigned* maxslot = (unsigned*)(start + bseg + 1);

  ap_init<<<1, 1, 0, stream>>>(maxslot);
  ap_prep<<<16, 256, 0, stream>>>(W1, w1hi, w1lo);
  ap_mlp<<<(nrows + 63) / 64, 256, 0, stream>>>(x, w1hi, w1lo, b1, W2, b2, raw,
                                                maxslot, nrows);
  ap_bounds<<<(nrows + 255) / 256, 256, 0, stream>>>(batch, start, nrows, bseg);
  ap_segw<<<bseg, 256, 0, stream>>>(raw, start, maxslot, scale, nrows);
  ap_pool<<<bseg, 256, 0, stream>>>(x, raw, start, scale, maxslot, out);
}